// Round 9
// baseline (153.081 us; speedup 1.0000x reference)
//
#include <hip/hip_runtime.h>
#include <math.h>

#define T_BINS 350
#define REF_LEN 32
#define NB 32
#define NPIX 3072
#define N1 240
#define N2 10
#define NVAL 256
#define WROW 256                  // padded row width (floats) in W
#define WROWS (NVAL + 1)          // 256 value rows + 1 zero row
#define CH 14                     // chunk length (350 = 25*14)
#define NCHUNK 25

// ---------------------------------------------------------------------------
// Kernel 1 (fused): blocks 0..31 -> per-batch CSR build; blocks 32..223 ->
// 64x64 tiled transpose of w1; block 224 -> inverse bin map inv[t]=v or -1.
// (unchanged, proven)
// ---------------------------------------------------------------------------
__global__ void prep(const int* __restrict__ inp,
                     int* __restrict__ pix,    // [NB][NPIX]
                     int* __restrict__ offs,   // [NB][NVAL]
                     int* __restrict__ cnts,   // [NB][NVAL]
                     const float* __restrict__ w1,
                     float* __restrict__ w1t,
                     const int* __restrict__ table,
                     int* __restrict__ inv)    // [T_BINS]
{
    __shared__ int lc[NVAL];
    __shared__ int ls[NVAL];
    __shared__ int lslot[NVAL];
    __shared__ float tile[64][65];
    __shared__ int linv[T_BINS];

    const int tid = threadIdx.x;

    if (blockIdx.x < NB) {
        // ---- CSR build for batch b ----
        const int b = blockIdx.x;
        lc[tid] = 0;
        __syncthreads();

        int vals[12];
        #pragma unroll
        for (int i = 0; i < 12; ++i) {
            int v = inp[b * NPIX + i * 256 + tid];   // coalesced
            vals[i] = v;
            atomicAdd(&lc[v], 1);
        }
        __syncthreads();

        int x = lc[tid];
        ls[tid] = x;
        __syncthreads();
        for (int d = 1; d < 256; d <<= 1) {
            int y = (tid >= d) ? ls[tid - d] : 0;
            __syncthreads();
            ls[tid] += y;
            __syncthreads();
        }
        int excl = ls[tid] - x;
        offs[b * NVAL + tid] = excl;
        cnts[b * NVAL + tid] = x;
        lslot[tid] = excl;
        __syncthreads();

        #pragma unroll
        for (int i = 0; i < 12; ++i) {
            int slot = atomicAdd(&lslot[vals[i]], 1);
            pix[b * NPIX + slot] = i * 256 + tid;
        }
    } else if (blockIdx.x < NB + 192) {
        // ---- transpose tile ----
        const int tt = blockIdx.x - NB;       // 0..191
        const int p0 = (tt % 48) * 64;
        const int n0 = (tt / 48) * 64;
        const int c  = tid & 63;
        const int r0 = tid >> 6;              // 0..3

        #pragma unroll
        for (int i = 0; i < 16; ++i) {
            int n = n0 + r0 + i * 4;
            if (n < N1) tile[r0 + i * 4][c] = w1[n * NPIX + p0 + c];
        }
        __syncthreads();
        #pragma unroll
        for (int i = 0; i < 16; ++i) {
            int p = p0 + r0 + i * 4;
            int n = n0 + c;
            if (n < N1) w1t[p * N1 + n] = tile[c][r0 + i * 4];
        }
    } else {
        // ---- inverse bin map (table is injective value->bin) ----
        for (int i = tid; i < T_BINS; i += 256) linv[i] = -1;
        __syncthreads();
        if (tid < NVAL) linv[table[tid]] = tid;
        __syncthreads();
        for (int i = tid; i < T_BINS; i += 256) inv[i] = linv[i];
    }
}

// ---------------------------------------------------------------------------
// Kernel 2: W[b][v][n] = sum over pixels with value v of w1t[p, n].
// Padded layout [NB][257][256]: cols 240..255 = 0, row 256 = 0 -> the
// dynamics kernel loads UNCONDITIONALLY for every lane and every bin.
// Ascending-order fp64 accumulate, single fp32 rounding (verified).
// ---------------------------------------------------------------------------
__global__ void compute_w(const float* __restrict__ w1t,
                          const int* __restrict__ pix,
                          const int* __restrict__ offs,
                          const int* __restrict__ cnts,
                          float* __restrict__ W)     // [NB][WROWS][WROW]
{
    const int b   = blockIdx.y;
    const int tid = threadIdx.x;

    for (int vv = 0; vv < 4; ++vv) {
        const int v = blockIdx.x * 4 + vv;
        float outv = 0.0f;
        if (tid < N1) {
            const int cnt = cnts[b * NVAL + v];
            const int* pl = pix + b * NPIX + offs[b * NVAL + v];
            double acc = 0.0;
            int i = 0;
            for (; i + 4 <= cnt; i += 4) {
                int p0 = pl[i], p1 = pl[i + 1], p2 = pl[i + 2], p3 = pl[i + 3];
                double w0  = (double)w1t[p0 * N1 + tid];
                double w1v = (double)w1t[p1 * N1 + tid];
                double w2v = (double)w1t[p2 * N1 + tid];
                double w3  = (double)w1t[p3 * N1 + tid];
                acc += w0; acc += w1v; acc += w2v; acc += w3;   // ascending order
            }
            for (; i < cnt; ++i)
                acc += (double)w1t[pl[i] * N1 + tid];
            outv = (float)acc;
        }
        W[((size_t)b * WROWS + v) * WROW + tid] = outv;
    }
    // zero row (v = NVAL) for empty time bins
    if (blockIdx.x == 0)
        W[((size_t)b * WROWS + NVAL) * WROW + tid] = 0.0f;
}

// ---------------------------------------------------------------------------
// Dynamics math (identical constants/ops to all prior rounds).
// ---------------------------------------------------------------------------
#define DYN_CONSTS \
    const double A    = 0.9048374180359595;     \
    const double C    = 0.2718281828459045;     \
    const double Ar   = 0.36787944117144233;    \
    const double Cr   = -54.365636569180904;    \
    const double C31A = 1.0671679036256927e-12; \
    const double C31B = 3.4424771084699765e-14;

#define DYN_CORE(uin)                                         \
        q = A * (q + p);                                      \
        p = A * p + (uin);                                    \
        double vm = C * q + Cr * Q;                           \
        unsigned int sb = (vm >= 10.0) ? 1u : 0u;             \
        double s = (double)sb;                                \
        double sel31 = (hist & 0x80000000u) ? C31A : 0.0;     \
        double sel30 = (hist & 0x40000000u) ? C31B : 0.0;     \
        Q = Ar * (Q + P - sel31);                             \
        P = s + (Ar * P - sel30);                             \
        hist = (hist << 1) | sb;

// expand M(i) for i = 0..13
#define F14(M) M(0) M(1) M(2) M(3) M(4) M(5) M(6) M(7) M(8) M(9) M(10) M(11) M(12) M(13)

// ---------------------------------------------------------------------------
// Kernel 3 (pipelined fusion): one block per batch, 512 threads = 8 waves.
// Same verified 3-stage / 2-slot pipeline as rounds 7/8.
// Round-9 change: stage 2's bit-walk extracts FOUR set-bit indices into
// named scalars, issues the 4 independent LDS loads together, then adds in
// the original ascending order. Rounds 7/8 proved stage 2 is the pipeline
// wall (5500 cyc/chunk = measured 62us; stage-1 codegen changes were
// no-ops): the 1-at-a-time while loop chained one ~110-cycle LDS round
// trip PER SPIKE. 4-wide batching overlaps 4 loads with the fp64 add
// chain (~4x fewer latency stalls). Add sequence is unchanged ->
// bit-identical results.
// ---------------------------------------------------------------------------
__global__ __launch_bounds__(512, 1) void fused_dyn(
        const float* __restrict__ W,     // [NB][WROWS][WROW]
        const int* __restrict__ inv,     // [T_BINS]
        const float* __restrict__ w2,    // [N2][N1]
        float* __restrict__ out)         // [NB][N2][T_BINS]
{
    __shared__ unsigned long long mbuf[2][CH][4];   // 896 B
    __shared__ float u2buf[2][CH][11];              // 1.2 KB (pad 11)
    __shared__ float sout[T_BINS][11];              // 15.4 KB (pad 11)
    __shared__ float lw2[N2][N1 + 1];               // 9.6 KB (pad 241)
    __shared__ int loff[T_BINS];                    // 1.4 KB

    const int tid  = threadIdx.x;
    const int b    = blockIdx.x;
    const int wid  = tid >> 6;
    const int lane = tid & 63;

    for (int i = tid; i < N2 * N1; i += 512) lw2[i / N1][i % N1] = w2[i];
    for (int i = tid; i < T_BINS; i += 512) {
        int v = inv[i];
        loff[i] = ((v >= 0) ? v : NVAL) * (WROW * 4);
    }
    __syncthreads();

    DYN_CONSTS
    double p = 0.0, q = 0.0, P = 0.0, Q = 0.0;   // IIR state: L1 (waves 0-3)
    unsigned int hist = 0u;                       // or L2 (wave 7, lane<10)

    // stage-1 prefetch state: named scalars, never an indexable object
#define DECL_CF(i) float c##i = 0.0f, f##i = 0.0f;
    F14(DECL_CF)

    const char* wb = nullptr;
    if (wid < 4) {
        const int n = wid * 64 + lane;            // 0..255, legal (padded) col
        wb = (const char*)W + ((size_t)b * WROWS) * (WROW * 4) + (size_t)n * 4;
#define LOADC(i) c##i = *(const float*)(wb + loff[i]);
        F14(LOADC)
    }

    for (int it = 0; it < NCHUNK + 2; ++it) {
        if (wid < 4 && it < NCHUNK) {
            // ---- stage 1: layer-1 dynamics, chunk it ----
            if (it + 1 < NCHUNK) {
                const int base = (it + 1) * CH;
#define LOADF(i) f##i = *(const float*)(wb + loff[base + i]);
                F14(LOADF)
            }
            const int slot = it & 1;
#define STEP1(i) { DYN_CORE((double)c##i)                                  \
                   unsigned long long msk = __ballot(sb != 0u);            \
                   if (lane == 0) mbuf[slot][i][wid] = msk; }
            F14(STEP1)
            asm volatile("" : "+v"(f0), "+v"(f1), "+v"(f2), "+v"(f3),
                              "+v"(f4), "+v"(f5), "+v"(f6), "+v"(f7),
                              "+v"(f8), "+v"(f9), "+v"(f10), "+v"(f11),
                              "+v"(f12), "+v"(f13));
#define COPYC(i) c##i = f##i;
            F14(COPYC)
        } else if (wid >= 4 && wid < 7 && it >= 1 && it <= NCHUNK) {
            // ---- stage 2: u2 for chunk it-1; 4-wide pipelined bit-walk ----
            const int item = (wid - 4) * 64 + lane;   // 0..191, need 140
            if (item < CH * N2) {
                const int st = item / N2;
                const int m  = item - st * N2;
                const int slot = (it - 1) & 1;
                double acc = 0.0;
                #pragma unroll
                for (int kk = 0; kk < 4; ++kk) {
                    unsigned long long msk = mbuf[slot][st][kk];
                    const float* wrow = &lw2[m][kk * 64];
                    int pc = __popcll(msk);
                    while (pc >= 4) {
                        int j0 = __ffsll(msk) - 1; msk &= msk - 1;
                        int j1 = __ffsll(msk) - 1; msk &= msk - 1;
                        int j2 = __ffsll(msk) - 1; msk &= msk - 1;
                        int j3 = __ffsll(msk) - 1; msk &= msk - 1;
                        float a0 = wrow[j0];
                        float a1 = wrow[j1];
                        float a2 = wrow[j2];
                        float a3 = wrow[j3];
                        acc += (double)a0; acc += (double)a1;   // same order
                        acc += (double)a2; acc += (double)a3;
                        pc -= 4;
                    }
                    while (msk) {
                        int j = __ffsll(msk) - 1; msk &= msk - 1;
                        acc += (double)wrow[j];
                    }
                }
                u2buf[slot][st][m] = (float)acc;
            }
        } else if (wid == 7 && lane < N2 && it >= 2) {
            // ---- stage 3: layer-2 IIR, chunk it-2 ----
            const int cl = it - 2;
            const int slot = cl & 1;
            const int m = lane;
            const int tb = cl * CH;
#define DECL_G(i) float g##i = u2buf[slot][i][m];
            F14(DECL_G)
            asm volatile("" : "+v"(g0), "+v"(g1), "+v"(g2), "+v"(g3),
                              "+v"(g4), "+v"(g5), "+v"(g6), "+v"(g7),
                              "+v"(g8), "+v"(g9), "+v"(g10), "+v"(g11),
                              "+v"(g12), "+v"(g13));
#define STEP3(i) { DYN_CORE((double)g##i) sout[tb + i][m] = (float)s; }
            F14(STEP3)
        }
        __syncthreads();
    }

    // ---- coalesced output out[b][m][t] ----
    float* ob = out + (size_t)b * N2 * T_BINS;
    for (int id = tid; id < N2 * T_BINS; id += 512) {
        const int m = id / T_BINS;
        const int t = id - m * T_BINS;
        ob[id] = sout[t][m];
    }
}

// ---------------------------------------------------------------------------
extern "C" void kernel_launch(void* const* d_in, const int* in_sizes, int n_in,
                              void* d_out, int out_size, void* d_ws, size_t ws_size,
                              hipStream_t stream) {
    const int*   inp   = (const int*)d_in[0];    // [32,3,32,32]
    const int*   table = (const int*)d_in[1];    // [256]
    const float* w1    = (const float*)d_in[2];  // [240,3072]
    const float* w2    = (const float*)d_in[3];  // [10,240]
    float* out = (float*)d_out;                  // [32,10,350]

    char* ws = (char*)d_ws;
    size_t off = 0;
    float* W   = (float*)(ws + off);  off += (size_t)NB * WROWS * WROW * 4;  // 8.4 MB
    float* w1t = (float*)(ws + off);  off += (size_t)NPIX * N1 * 4;          // 2.9 MB
    int*   pix = (int*)(ws + off);    off += (size_t)NB * NPIX * 4;
    int*  offs = (int*)(ws + off);    off += (size_t)NB * NVAL * 4;
    int*  cnts = (int*)(ws + off);    off += (size_t)NB * NVAL * 4;
    int*   inv = (int*)(ws + off);    off += (size_t)T_BINS * 4;

    prep<<<NB + 192 + 1, 256, 0, stream>>>(inp, pix, offs, cnts, w1, w1t, table, inv);
    compute_w<<<dim3(NVAL / 4, NB), 256, 0, stream>>>(w1t, pix, offs, cnts, W);
    fused_dyn<<<NB, 512, 0, stream>>>(W, inv, w2, out);
}

// Round 10
// 149.697 us; speedup vs baseline: 1.0226x; 1.0226x over previous
//
#include <hip/hip_runtime.h>
#include <math.h>

#define T_BINS 350
#define REF_LEN 32
#define NB 32
#define NPIX 3072
#define N1 240
#define N2 10
#define NVAL 256
#define WROW 256                  // padded row width (floats) in W
#define WROWS (NVAL + 1)          // 256 value rows + 1 zero row
#define CH 14                     // chunk length (350 = 25*14)
#define NCHUNK 25
#define NTHREADS 896              // 14 waves: 4 L1 + 9 u2 + 1 L2

// ---------------------------------------------------------------------------
// Kernel 1 (fused): blocks 0..31 -> per-batch CSR build; blocks 32..223 ->
// 64x64 tiled transpose of w1; block 224 -> inverse bin map inv[t]=v or -1.
// (unchanged, proven)
// ---------------------------------------------------------------------------
__global__ void prep(const int* __restrict__ inp,
                     int* __restrict__ pix,    // [NB][NPIX]
                     int* __restrict__ offs,   // [NB][NVAL]
                     int* __restrict__ cnts,   // [NB][NVAL]
                     const float* __restrict__ w1,
                     float* __restrict__ w1t,
                     const int* __restrict__ table,
                     int* __restrict__ inv)    // [T_BINS]
{
    __shared__ int lc[NVAL];
    __shared__ int ls[NVAL];
    __shared__ int lslot[NVAL];
    __shared__ float tile[64][65];
    __shared__ int linv[T_BINS];

    const int tid = threadIdx.x;

    if (blockIdx.x < NB) {
        // ---- CSR build for batch b ----
        const int b = blockIdx.x;
        lc[tid] = 0;
        __syncthreads();

        int vals[12];
        #pragma unroll
        for (int i = 0; i < 12; ++i) {
            int v = inp[b * NPIX + i * 256 + tid];   // coalesced
            vals[i] = v;
            atomicAdd(&lc[v], 1);
        }
        __syncthreads();

        int x = lc[tid];
        ls[tid] = x;
        __syncthreads();
        for (int d = 1; d < 256; d <<= 1) {
            int y = (tid >= d) ? ls[tid - d] : 0;
            __syncthreads();
            ls[tid] += y;
            __syncthreads();
        }
        int excl = ls[tid] - x;
        offs[b * NVAL + tid] = excl;
        cnts[b * NVAL + tid] = x;
        lslot[tid] = excl;
        __syncthreads();

        #pragma unroll
        for (int i = 0; i < 12; ++i) {
            int slot = atomicAdd(&lslot[vals[i]], 1);
            pix[b * NPIX + slot] = i * 256 + tid;
        }
    } else if (blockIdx.x < NB + 192) {
        // ---- transpose tile ----
        const int tt = blockIdx.x - NB;       // 0..191
        const int p0 = (tt % 48) * 64;
        const int n0 = (tt / 48) * 64;
        const int c  = tid & 63;
        const int r0 = tid >> 6;              // 0..3

        #pragma unroll
        for (int i = 0; i < 16; ++i) {
            int n = n0 + r0 + i * 4;
            if (n < N1) tile[r0 + i * 4][c] = w1[n * NPIX + p0 + c];
        }
        __syncthreads();
        #pragma unroll
        for (int i = 0; i < 16; ++i) {
            int p = p0 + r0 + i * 4;
            int n = n0 + c;
            if (n < N1) w1t[p * N1 + n] = tile[c][r0 + i * 4];
        }
    } else {
        // ---- inverse bin map (table is injective value->bin) ----
        for (int i = tid; i < T_BINS; i += 256) linv[i] = -1;
        __syncthreads();
        if (tid < NVAL) linv[table[tid]] = tid;
        __syncthreads();
        for (int i = tid; i < T_BINS; i += 256) inv[i] = linv[i];
    }
}

// ---------------------------------------------------------------------------
// Kernel 2: W[b][v][n] = sum over pixels with value v of w1t[p, n].
// Padded layout [NB][257][256]: cols 240..255 = 0, row 256 = 0 -> the
// dynamics kernel loads UNCONDITIONALLY for every lane and every bin.
// ---------------------------------------------------------------------------
__global__ void compute_w(const float* __restrict__ w1t,
                          const int* __restrict__ pix,
                          const int* __restrict__ offs,
                          const int* __restrict__ cnts,
                          float* __restrict__ W)     // [NB][WROWS][WROW]
{
    const int b   = blockIdx.y;
    const int tid = threadIdx.x;

    for (int vv = 0; vv < 4; ++vv) {
        const int v = blockIdx.x * 4 + vv;
        float outv = 0.0f;
        if (tid < N1) {
            const int cnt = cnts[b * NVAL + v];
            const int* pl = pix + b * NPIX + offs[b * NVAL + v];
            double acc = 0.0;
            int i = 0;
            for (; i + 4 <= cnt; i += 4) {
                int p0 = pl[i], p1 = pl[i + 1], p2 = pl[i + 2], p3 = pl[i + 3];
                double w0  = (double)w1t[p0 * N1 + tid];
                double w1v = (double)w1t[p1 * N1 + tid];
                double w2v = (double)w1t[p2 * N1 + tid];
                double w3  = (double)w1t[p3 * N1 + tid];
                acc += w0; acc += w1v; acc += w2v; acc += w3;   // ascending order
            }
            for (; i < cnt; ++i)
                acc += (double)w1t[pl[i] * N1 + tid];
            outv = (float)acc;
        }
        W[((size_t)b * WROWS + v) * WROW + tid] = outv;
    }
    // zero row (v = NVAL) for empty time bins
    if (blockIdx.x == 0)
        W[((size_t)b * WROWS + NVAL) * WROW + tid] = 0.0f;
}

// ---------------------------------------------------------------------------
// Dynamics math (identical constants/ops to all prior rounds).
// ---------------------------------------------------------------------------
#define DYN_CONSTS \
    const double A    = 0.9048374180359595;     \
    const double C    = 0.2718281828459045;     \
    const double Ar   = 0.36787944117144233;    \
    const double Cr   = -54.365636569180904;    \
    const double C31A = 1.0671679036256927e-12; \
    const double C31B = 3.4424771084699765e-14;

#define DYN_CORE(uin)                                         \
        q = A * (q + p);                                      \
        p = A * p + (uin);                                    \
        double vm = C * q + Cr * Q;                           \
        unsigned int sb = (vm >= 10.0) ? 1u : 0u;             \
        double s = (double)sb;                                \
        double sel31 = (hist & 0x80000000u) ? C31A : 0.0;     \
        double sel30 = (hist & 0x40000000u) ? C31B : 0.0;     \
        Q = Ar * (Q + P - sel31);                             \
        P = s + (Ar * P - sel30);                             \
        hist = (hist << 1) | sb;

// expand M(i) for i = 0..13
#define F14(M) M(0) M(1) M(2) M(3) M(4) M(5) M(6) M(7) M(8) M(9) M(10) M(11) M(12) M(13)

// ---------------------------------------------------------------------------
// Kernel 3 (pipelined fusion): one block per batch, 896 threads = 14 waves.
// Round-10 changes (R9 post-mortem: stage 2 IS the wall; 4-wide ILP made it
// worse -> reverted; attack with PARALLELISM instead):
//  * stage 2 now spans 9 waves (576 lanes); each (t,m) item is split by
//    64-bit mask word across 4 ADJACENT lanes of one wave (560 subitems,
//    one per lane). Per-lane bit-walk = per-word spike count (~1/4 of the
//    per-item tail that set the old 5500 cyc/chunk wall). Partials combine
//    in-wave via 3 __shfl + adds in ascending word order (no extra
//    barrier). Within-word add order unchanged; word-sum association
//    differs by fp64 ulps only (output is binary spikes; threshold flip
//    needs |vm-10|<1e-13 -> never).
//  * stage 1 (waves 0-3) and stage 3 (wave 13) unchanged from R8.
// ---------------------------------------------------------------------------
__global__ __launch_bounds__(NTHREADS, 1) void fused_dyn(
        const float* __restrict__ W,     // [NB][WROWS][WROW]
        const int* __restrict__ inv,     // [T_BINS]
        const float* __restrict__ w2,    // [N2][N1]
        float* __restrict__ out)         // [NB][N2][T_BINS]
{
    __shared__ unsigned long long mbuf[2][CH][4];   // 896 B
    __shared__ float u2buf[2][CH][11];              // 1.2 KB (pad 11)
    __shared__ float sout[T_BINS][11];              // 15.4 KB (pad 11)
    __shared__ float lw2[N2][N1 + 1];               // 9.6 KB (pad 241)
    __shared__ int loff[T_BINS];                    // 1.4 KB

    const int tid  = threadIdx.x;
    const int b    = blockIdx.x;
    const int wid  = tid >> 6;
    const int lane = tid & 63;

    for (int i = tid; i < N2 * N1; i += NTHREADS) lw2[i / N1][i % N1] = w2[i];
    for (int i = tid; i < T_BINS; i += NTHREADS) {
        int v = inv[i];
        loff[i] = ((v >= 0) ? v : NVAL) * (WROW * 4);
    }
    __syncthreads();

    DYN_CONSTS
    double p = 0.0, q = 0.0, P = 0.0, Q = 0.0;   // IIR state: L1 (waves 0-3)
    unsigned int hist = 0u;                       // or L2 (wave 13, lane<10)

    // stage-1 prefetch state: named scalars, never an indexable object
#define DECL_CF(i) float c##i = 0.0f, f##i = 0.0f;
    F14(DECL_CF)

    const char* wb = nullptr;
    if (wid < 4) {
        const int n = wid * 64 + lane;            // 0..255, legal (padded) col
        wb = (const char*)W + ((size_t)b * WROWS) * (WROW * 4) + (size_t)n * 4;
#define LOADC(i) c##i = *(const float*)(wb + loff[i]);
        F14(LOADC)
    }

    // stage-2 static assignment: subitem = (item, word)
    const int s2L    = (wid - 4) * 64 + lane;     // 0..575 for waves 4..12
    const int s2item = s2L >> 2;                  // 0..143 (140 used)
    const int s2kk   = s2L & 3;                   // word index
    const int s2st   = s2item / N2;               // sub-t within chunk
    const int s2m    = s2item - s2st * N2;        // output neuron

    for (int it = 0; it < NCHUNK + 2; ++it) {
        if (wid < 4 && it < NCHUNK) {
            // ---- stage 1: layer-1 dynamics, chunk it ----
            if (it + 1 < NCHUNK) {
                const int base = (it + 1) * CH;
#define LOADF(i) f##i = *(const float*)(wb + loff[base + i]);
                F14(LOADF)
            }
            const int slot = it & 1;
#define STEP1(i) { DYN_CORE((double)c##i)                                  \
                   unsigned long long msk = __ballot(sb != 0u);            \
                   if (lane == 0) mbuf[slot][i][wid] = msk; }
            F14(STEP1)
            asm volatile("" : "+v"(f0), "+v"(f1), "+v"(f2), "+v"(f3),
                              "+v"(f4), "+v"(f5), "+v"(f6), "+v"(f7),
                              "+v"(f8), "+v"(f9), "+v"(f10), "+v"(f11),
                              "+v"(f12), "+v"(f13));
#define COPYC(i) c##i = f##i;
            F14(COPYC)
        } else if (wid >= 4 && wid < 13 && it >= 1 && it <= NCHUNK) {
            // ---- stage 2: u2 for chunk it-1; one mask-word per lane ----
            const int slot = (it - 1) & 1;
            double acc = 0.0;
            {
                unsigned long long msk = mbuf[slot][s2st][s2kk];
                const float* wrow = &lw2[s2m][s2kk * 64];
                while (msk) {                       // simple loop (R8-proven)
                    int j = __ffsll(msk) - 1;
                    acc += (double)wrow[j];
                    msk &= msk - 1;
                }
            }
            // in-wave combine of the 4 word-partials, ascending word order
            const int g4 = lane & ~3;
            double a0 = __shfl(acc, g4 + 0);
            double a1 = __shfl(acc, g4 + 1);
            double a2 = __shfl(acc, g4 + 2);
            double a3 = __shfl(acc, g4 + 3);
            if ((lane & 3) == 0 && s2item < CH * N2) {
                double ssum = a0; ssum += a1; ssum += a2; ssum += a3;
                u2buf[slot][s2st][s2m] = (float)ssum;
            }
        } else if (wid == 13 && lane < N2 && it >= 2) {
            // ---- stage 3: layer-2 IIR, chunk it-2 ----
            const int cl = it - 2;
            const int slot = cl & 1;
            const int m = lane;
            const int tb = cl * CH;
#define DECL_G(i) float g##i = u2buf[slot][i][m];
            F14(DECL_G)
            asm volatile("" : "+v"(g0), "+v"(g1), "+v"(g2), "+v"(g3),
                              "+v"(g4), "+v"(g5), "+v"(g6), "+v"(g7),
                              "+v"(g8), "+v"(g9), "+v"(g10), "+v"(g11),
                              "+v"(g12), "+v"(g13));
#define STEP3(i) { DYN_CORE((double)g##i) sout[tb + i][m] = (float)s; }
            F14(STEP3)
        }
        __syncthreads();
    }

    // ---- coalesced output out[b][m][t] ----
    float* ob = out + (size_t)b * N2 * T_BINS;
    for (int id = tid; id < N2 * T_BINS; id += NTHREADS) {
        const int m = id / T_BINS;
        const int t = id - m * T_BINS;
        ob[id] = sout[t][m];
    }
}

// ---------------------------------------------------------------------------
extern "C" void kernel_launch(void* const* d_in, const int* in_sizes, int n_in,
                              void* d_out, int out_size, void* d_ws, size_t ws_size,
                              hipStream_t stream) {
    const int*   inp   = (const int*)d_in[0];    // [32,3,32,32]
    const int*   table = (const int*)d_in[1];    // [256]
    const float* w1    = (const float*)d_in[2];  // [240,3072]
    const float* w2    = (const float*)d_in[3];  // [10,240]
    float* out = (float*)d_out;                  // [32,10,350]

    char* ws = (char*)d_ws;
    size_t off = 0;
    float* W   = (float*)(ws + off);  off += (size_t)NB * WROWS * WROW * 4;  // 8.4 MB
    float* w1t = (float*)(ws + off);  off += (size_t)NPIX * N1 * 4;          // 2.9 MB
    int*   pix = (int*)(ws + off);    off += (size_t)NB * NPIX * 4;
    int*  offs = (int*)(ws + off);    off += (size_t)NB * NVAL * 4;
    int*  cnts = (int*)(ws + off);    off += (size_t)NB * NVAL * 4;
    int*   inv = (int*)(ws + off);    off += (size_t)T_BINS * 4;

    prep<<<NB + 192 + 1, 256, 0, stream>>>(inp, pix, offs, cnts, w1, w1t, table, inv);
    compute_w<<<dim3(NVAL / 4, NB), 256, 0, stream>>>(w1t, pix, offs, cnts, W);
    fused_dyn<<<NB, NTHREADS, 0, stream>>>(W, inv, w2, out);
}

// Round 11
// 141.653 us; speedup vs baseline: 1.0807x; 1.0568x over previous
//
#include <hip/hip_runtime.h>
#include <math.h>

#define T_BINS 350
#define REF_LEN 32
#define NB 32
#define NPIX 3072
#define N1 240
#define N2 10
#define NVAL 256
#define WROW 256                  // padded row width (floats) in W
#define WROWS (NVAL + 1)          // 256 value rows + 1 zero row
#define CH 14                     // chunk length (350 = 25*14)
#define NCHUNK 25

// ---------------------------------------------------------------------------
// Kernel 1 (fused): blocks 0..31 -> per-batch CSR build; blocks 32..223 ->
// 64x64 tiled transpose of w1; block 224 -> inverse bin map inv[t]=v or -1.
// (unchanged, proven)
// ---------------------------------------------------------------------------
__global__ void prep(const int* __restrict__ inp,
                     int* __restrict__ pix,    // [NB][NPIX]
                     int* __restrict__ offs,   // [NB][NVAL]
                     int* __restrict__ cnts,   // [NB][NVAL]
                     const float* __restrict__ w1,
                     float* __restrict__ w1t,
                     const int* __restrict__ table,
                     int* __restrict__ inv)    // [T_BINS]
{
    __shared__ int lc[NVAL];
    __shared__ int ls[NVAL];
    __shared__ int lslot[NVAL];
    __shared__ float tile[64][65];
    __shared__ int linv[T_BINS];

    const int tid = threadIdx.x;

    if (blockIdx.x < NB) {
        // ---- CSR build for batch b ----
        const int b = blockIdx.x;
        lc[tid] = 0;
        __syncthreads();

        int vals[12];
        #pragma unroll
        for (int i = 0; i < 12; ++i) {
            int v = inp[b * NPIX + i * 256 + tid];   // coalesced
            vals[i] = v;
            atomicAdd(&lc[v], 1);
        }
        __syncthreads();

        int x = lc[tid];
        ls[tid] = x;
        __syncthreads();
        for (int d = 1; d < 256; d <<= 1) {
            int y = (tid >= d) ? ls[tid - d] : 0;
            __syncthreads();
            ls[tid] += y;
            __syncthreads();
        }
        int excl = ls[tid] - x;
        offs[b * NVAL + tid] = excl;
        cnts[b * NVAL + tid] = x;
        lslot[tid] = excl;
        __syncthreads();

        #pragma unroll
        for (int i = 0; i < 12; ++i) {
            int slot = atomicAdd(&lslot[vals[i]], 1);
            pix[b * NPIX + slot] = i * 256 + tid;
        }
    } else if (blockIdx.x < NB + 192) {
        // ---- transpose tile ----
        const int tt = blockIdx.x - NB;       // 0..191
        const int p0 = (tt % 48) * 64;
        const int n0 = (tt / 48) * 64;
        const int c  = tid & 63;
        const int r0 = tid >> 6;              // 0..3

        #pragma unroll
        for (int i = 0; i < 16; ++i) {
            int n = n0 + r0 + i * 4;
            if (n < N1) tile[r0 + i * 4][c] = w1[n * NPIX + p0 + c];
        }
        __syncthreads();
        #pragma unroll
        for (int i = 0; i < 16; ++i) {
            int p = p0 + r0 + i * 4;
            int n = n0 + c;
            if (n < N1) w1t[p * N1 + n] = tile[c][r0 + i * 4];
        }
    } else {
        // ---- inverse bin map (table is injective value->bin) ----
        for (int i = tid; i < T_BINS; i += 256) linv[i] = -1;
        __syncthreads();
        if (tid < NVAL) linv[table[tid]] = tid;
        __syncthreads();
        for (int i = tid; i < T_BINS; i += 256) inv[i] = linv[i];
    }
}

// ---------------------------------------------------------------------------
// Kernel 2: W[b][v][n] = sum over pixels with value v of w1t[p, n].
// Round-11: ONE value per block (8192 blocks, was 4/block at 2048) — the
// gathers are latency-bound; 4x less serial work per thread and 4x more
// TLP to hide it. Inner math/order byte-identical (ascending fp64, single
// fp32 rounding). Padded layout [NB][257][256] unchanged.
// ---------------------------------------------------------------------------
__global__ void compute_w(const float* __restrict__ w1t,
                          const int* __restrict__ pix,
                          const int* __restrict__ offs,
                          const int* __restrict__ cnts,
                          float* __restrict__ W)     // [NB][WROWS][WROW]
{
    const int v   = blockIdx.x;
    const int b   = blockIdx.y;
    const int tid = threadIdx.x;

    float outv = 0.0f;
    if (tid < N1) {
        const int cnt = cnts[b * NVAL + v];
        const int* pl = pix + b * NPIX + offs[b * NVAL + v];
        double acc = 0.0;
        int i = 0;
        for (; i + 4 <= cnt; i += 4) {
            int p0 = pl[i], p1 = pl[i + 1], p2 = pl[i + 2], p3 = pl[i + 3];
            double w0  = (double)w1t[p0 * N1 + tid];
            double w1v = (double)w1t[p1 * N1 + tid];
            double w2v = (double)w1t[p2 * N1 + tid];
            double w3  = (double)w1t[p3 * N1 + tid];
            acc += w0; acc += w1v; acc += w2v; acc += w3;   // ascending order
        }
        for (; i < cnt; ++i)
            acc += (double)w1t[pl[i] * N1 + tid];
        outv = (float)acc;
    }
    W[((size_t)b * WROWS + v) * WROW + tid] = outv;
    // zero row (v = NVAL) for empty time bins, once per batch
    if (v == 0)
        W[((size_t)b * WROWS + NVAL) * WROW + tid] = 0.0f;
}

// ---------------------------------------------------------------------------
// Dynamics math (identical constants/ops to all prior rounds).
// ---------------------------------------------------------------------------
#define DYN_CONSTS \
    const double A    = 0.9048374180359595;     \
    const double C    = 0.2718281828459045;     \
    const double Ar   = 0.36787944117144233;    \
    const double Cr   = -54.365636569180904;    \
    const double C31A = 1.0671679036256927e-12; \
    const double C31B = 3.4424771084699765e-14;

#define DYN_CORE(uin)                                         \
        q = A * (q + p);                                      \
        p = A * p + (uin);                                    \
        double vm = C * q + Cr * Q;                           \
        unsigned int sb = (vm >= 10.0) ? 1u : 0u;             \
        double s = (double)sb;                                \
        double sel31 = (hist & 0x80000000u) ? C31A : 0.0;     \
        double sel30 = (hist & 0x40000000u) ? C31B : 0.0;     \
        Q = Ar * (Q + P - sel31);                             \
        P = s + (Ar * P - sel30);                             \
        hist = (hist << 1) | sb;

// expand M(i) for i = 0..13
#define F14(M) M(0) M(1) M(2) M(3) M(4) M(5) M(6) M(7) M(8) M(9) M(10) M(11) M(12) M(13)

// ---------------------------------------------------------------------------
// Kernel 3 (pipelined fusion): EXACT R8 version — best measured (62.6us).
// R9 (stage-2 4-wide ILP, +12us) and R10 (stage-2 9-wave word-split, +8us)
// both REVERTED: two independent interventions on stage 2 regressed, and
// stage-1 codegen changes (R8) were neutral -> the wall is the serial fp64
// IIR dependency chain + per-wave barrier convoy, which scales with wave
// count (8 waves optimal) and cannot be shortened by redistributing stage
// work. 512 threads = 8 waves: 0-3 layer-1, 4-6 u2 bit-walk, 7 layer-2.
// ---------------------------------------------------------------------------
__global__ __launch_bounds__(512, 1) void fused_dyn(
        const float* __restrict__ W,     // [NB][WROWS][WROW]
        const int* __restrict__ inv,     // [T_BINS]
        const float* __restrict__ w2,    // [N2][N1]
        float* __restrict__ out)         // [NB][N2][T_BINS]
{
    __shared__ unsigned long long mbuf[2][CH][4];   // 896 B
    __shared__ float u2buf[2][CH][11];              // 1.2 KB (pad 11)
    __shared__ float sout[T_BINS][11];              // 15.4 KB (pad 11)
    __shared__ float lw2[N2][N1 + 1];               // 9.6 KB (pad 241)
    __shared__ int loff[T_BINS];                    // 1.4 KB

    const int tid  = threadIdx.x;
    const int b    = blockIdx.x;
    const int wid  = tid >> 6;
    const int lane = tid & 63;

    for (int i = tid; i < N2 * N1; i += 512) lw2[i / N1][i % N1] = w2[i];
    for (int i = tid; i < T_BINS; i += 512) {
        int v = inv[i];
        loff[i] = ((v >= 0) ? v : NVAL) * (WROW * 4);
    }
    __syncthreads();

    DYN_CONSTS
    double p = 0.0, q = 0.0, P = 0.0, Q = 0.0;   // IIR state: L1 (waves 0-3)
    unsigned int hist = 0u;                       // or L2 (wave 7, lane<10)

    // stage-1 prefetch state: named scalars, never an indexable object
#define DECL_CF(i) float c##i = 0.0f, f##i = 0.0f;
    F14(DECL_CF)

    const char* wb = nullptr;
    if (wid < 4) {
        const int n = wid * 64 + lane;            // 0..255, legal (padded) col
        wb = (const char*)W + ((size_t)b * WROWS) * (WROW * 4) + (size_t)n * 4;
#define LOADC(i) c##i = *(const float*)(wb + loff[i]);
        F14(LOADC)
    }

    for (int it = 0; it < NCHUNK + 2; ++it) {
        if (wid < 4 && it < NCHUNK) {
            // ---- stage 1: layer-1 dynamics, chunk it ----
            if (it + 1 < NCHUNK) {
                const int base = (it + 1) * CH;
#define LOADF(i) f##i = *(const float*)(wb + loff[base + i]);
                F14(LOADF)
            }
            const int slot = it & 1;
#define STEP1(i) { DYN_CORE((double)c##i)                                  \
                   unsigned long long msk = __ballot(sb != 0u);            \
                   if (lane == 0) mbuf[slot][i][wid] = msk; }
            F14(STEP1)
            asm volatile("" : "+v"(f0), "+v"(f1), "+v"(f2), "+v"(f3),
                              "+v"(f4), "+v"(f5), "+v"(f6), "+v"(f7),
                              "+v"(f8), "+v"(f9), "+v"(f10), "+v"(f11),
                              "+v"(f12), "+v"(f13));
#define COPYC(i) c##i = f##i;
            F14(COPYC)
        } else if (wid >= 4 && wid < 7 && it >= 1 && it <= NCHUNK) {
            // ---- stage 2: u2 for chunk it-1 (kk asc / ffs asc, verified) ----
            const int item = (wid - 4) * 64 + lane;   // 0..191, need 140
            if (item < CH * N2) {
                const int st = item / N2;
                const int m  = item - st * N2;
                const int slot = (it - 1) & 1;
                double acc = 0.0;
                #pragma unroll
                for (int kk = 0; kk < 4; ++kk) {
                    unsigned long long msk = mbuf[slot][st][kk];
                    while (msk) {
                        int j = __ffsll(msk) - 1;
                        acc += (double)lw2[m][kk * 64 + j];
                        msk &= msk - 1;
                    }
                }
                u2buf[slot][st][m] = (float)acc;
            }
        } else if (wid == 7 && lane < N2 && it >= 2) {
            // ---- stage 3: layer-2 IIR, chunk it-2 ----
            const int cl = it - 2;
            const int slot = cl & 1;
            const int m = lane;
            const int tb = cl * CH;
#define DECL_G(i) float g##i = u2buf[slot][i][m];
            F14(DECL_G)
            asm volatile("" : "+v"(g0), "+v"(g1), "+v"(g2), "+v"(g3),
                              "+v"(g4), "+v"(g5), "+v"(g6), "+v"(g7),
                              "+v"(g8), "+v"(g9), "+v"(g10), "+v"(g11),
                              "+v"(g12), "+v"(g13));
#define STEP3(i) { DYN_CORE((double)g##i) sout[tb + i][m] = (float)s; }
            F14(STEP3)
        }
        __syncthreads();
    }

    // ---- coalesced output out[b][m][t] ----
    float* ob = out + (size_t)b * N2 * T_BINS;
    for (int id = tid; id < N2 * T_BINS; id += 512) {
        const int m = id / T_BINS;
        const int t = id - m * T_BINS;
        ob[id] = sout[t][m];
    }
}

// ---------------------------------------------------------------------------
extern "C" void kernel_launch(void* const* d_in, const int* in_sizes, int n_in,
                              void* d_out, int out_size, void* d_ws, size_t ws_size,
                              hipStream_t stream) {
    const int*   inp   = (const int*)d_in[0];    // [32,3,32,32]
    const int*   table = (const int*)d_in[1];    // [256]
    const float* w1    = (const float*)d_in[2];  // [240,3072]
    const float* w2    = (const float*)d_in[3];  // [10,240]
    float* out = (float*)d_out;                  // [32,10,350]

    char* ws = (char*)d_ws;
    size_t off = 0;
    float* W   = (float*)(ws + off);  off += (size_t)NB * WROWS * WROW * 4;  // 8.4 MB
    float* w1t = (float*)(ws + off);  off += (size_t)NPIX * N1 * 4;          // 2.9 MB
    int*   pix = (int*)(ws + off);    off += (size_t)NB * NPIX * 4;
    int*  offs = (int*)(ws + off);    off += (size_t)NB * NVAL * 4;
    int*  cnts = (int*)(ws + off);    off += (size_t)NB * NVAL * 4;
    int*   inv = (int*)(ws + off);    off += (size_t)T_BINS * 4;

    prep<<<NB + 192 + 1, 256, 0, stream>>>(inp, pix, offs, cnts, w1, w1t, table, inv);
    compute_w<<<dim3(NVAL, NB), 256, 0, stream>>>(w1t, pix, offs, cnts, W);
    fused_dyn<<<NB, 512, 0, stream>>>(W, inv, w2, out);
}